// Round 3
// baseline (404.085 us; speedup 1.0000x reference)
//
#include <hip/hip_runtime.h>
#include <hip/hip_bf16.h>

namespace {

constexpr int T_STEPS = 256;
constexpr int HD = 50;   // hidden size
constexpr int HP = 64;   // padded hidden
constexpr int KST = 72;  // LDS row stride in bf16 elems (b128 reads land conflict-free; b64 writes 2-way=free)
constexpr int BT = 16;   // batch tile per block
constexpr int NW = 3;    // one wave per layer — minimizes LDS traffic (the R1 bottleneck)
constexpr int NTHR = NW * 64;  // 192

typedef __attribute__((ext_vector_type(8))) short bf16x8;
typedef __attribute__((ext_vector_type(4))) float f32x4;

__device__ __forceinline__ unsigned short f2bf(float x) {
  __hip_bfloat16 h = __float2bfloat16(x);
  return *reinterpret_cast<unsigned short*>(&h);
}
__device__ __forceinline__ float bf2f(unsigned short u) {
  __hip_bfloat16 h;
  *reinterpret_cast<unsigned short*>(&h) = u;
  return __bfloat162float(h);
}
__device__ __forceinline__ float fast_tanh(float x) {
  float e = __expf(2.0f * x);
  return 1.0f - 2.0f * __builtin_amdgcn_rcpf(e + 1.0f);
}

// Orientation: D[i][b] = sum_k W[i][k] * h[b][k]
//   A (M=i, K)  = weights, static in VGPRs (A[m=16*t + lane&15][k=quad*8+j])
//   B (K, N=b)  = h state, from LDS       (B[k=quad*8+j][n=lane&15])
//   C/D         = row(i)=16*t + quad*4+reg, col(b)=lane&15
// Wave w = layer L. Each wave computes ALL 4 M-tiles of its layer, so each
// B-frag (h tile) is read from LDS exactly once per consumer-layer — LDS
// traffic 122 KB/iter (R1, LDS-BW-bound) -> 32 KB/iter.
__global__ __launch_bounds__(NTHR, 1) void rnn3_kernel(
    const float* __restrict__ x,
    const float* __restrict__ Wih1, const float* __restrict__ Whh1,
    const float* __restrict__ bih1, const float* __restrict__ bhh1,
    const float* __restrict__ Wih2, const float* __restrict__ Whh2,
    const float* __restrict__ bih2, const float* __restrict__ bhh2,
    const float* __restrict__ Wih3, const float* __restrict__ Whh3,
    const float* __restrict__ bih3, const float* __restrict__ bhh3,
    const float* __restrict__ fcw, const float* __restrict__ fcb,
    float* __restrict__ out) {
  // h state, ping-pong: [pp][layer][hi/lo][b*KST + k] (bf16 bits), zero-padded k>=HD
  __shared__ unsigned short hbuf[2][3][2][BT * KST];
  // weight staging scratch: [hi/lo][i*KST + k]
  __shared__ unsigned short scr[2][HP * KST];

  const int tid = threadIdx.x;
  const int myL = tid >> 6;       // wave = layer 0..2
  const int lane = tid & 63;
  const int quad = lane >> 4;
  const int l15 = lane & 15;
  const int b0 = blockIdx.x * BT;

  // zero both ping-pong h buffers (initial state h_{-1}=0; also the i>=HD pad)
  {
    unsigned int* hz = reinterpret_cast<unsigned int*>(&hbuf[0][0][0][0]);
    const int n = 2 * 3 * 2 * BT * KST / 2;
    for (int i = tid; i < n; i += NTHR) hz[i] = 0u;
  }

  // ---- stage the five 50x50 matrices, split fp32 -> bf16 hi/lo ----
  // Wave keeps its own layer's A-frags for all 4 M-tiles:
  //   L0: slot0 = Whh1;  L1: slot0 = Wih2, slot1 = Whh2;  L2: slot0 = Wih3, slot1 = Whh3
  const float* mats[5] = {Whh1, Wih2, Whh2, Wih3, Whh3};
  constexpr int matL[5] = {0, 1, 1, 2, 2};
  constexpr int matS[5] = {0, 0, 1, 0, 1};
  bf16x8 wAh[2][4][2], wAl[2][4][2];  // [slot][tile][kstep]
#pragma unroll
  for (int sl = 0; sl < 2; ++sl)
#pragma unroll
    for (int t = 0; t < 4; ++t)
#pragma unroll
      for (int ks = 0; ks < 2; ++ks) { wAh[sl][t][ks] = bf16x8(0); wAl[sl][t][ks] = bf16x8(0); }

#pragma unroll
  for (int m = 0; m < 5; ++m) {
    __syncthreads();  // scratch free (and, first time, hbuf zeros ordered)
    const float* W = mats[m];
    for (int idx = tid; idx < HP * HP; idx += NTHR) {
      int i = idx >> 6, k = idx & 63;
      float v = (i < HD && k < HD) ? W[i * HD + k] : 0.0f;
      unsigned short hi = f2bf(v);
      float rem = v - bf2f(hi);
      scr[0][i * KST + k] = hi;
      scr[1][i * KST + k] = f2bf(rem);
    }
    __syncthreads();
    if (myL == matL[m]) {
      const int sl = matS[m];
#pragma unroll
      for (int t = 0; t < 4; ++t) {
        const int arow = 16 * t + l15;
#pragma unroll
        for (int ks = 0; ks < 2; ++ks) {
          wAh[sl][t][ks] = *reinterpret_cast<const bf16x8*>(&scr[0][arow * KST + 32 * ks + 8 * quad]);
          wAl[sl][t][ks] = *reinterpret_cast<const bf16x8*>(&scr[1][arow * KST + 32 * ks + 8 * quad]);
        }
      }
    }
  }

  // ---- per-lane C-row constants (i = 16t + 4*quad + r), zero-padded past HD ----
  const float* bi = (myL == 0) ? bih1 : (myL == 1) ? bih2 : bih3;
  const float* bh = (myL == 0) ? bhh1 : (myL == 1) ? bhh2 : bhh3;
  float bs[4][4], wx0[4][4], wx1[4][4];
#pragma unroll
  for (int t = 0; t < 4; ++t)
#pragma unroll
    for (int r = 0; r < 4; ++r) {
      int i = 16 * t + 4 * quad + r;
      bool v = i < HD;
      bs[t][r] = v ? (bi[i] + bh[i]) : 0.0f;
      wx0[t][r] = (v && myL == 0) ? Wih1[i * 2 + 0] : 0.0f;
      wx1[t][r] = (v && myL == 0) ? Wih1[i * 2 + 1] : 0.0f;
    }

  // x for this lane's batch column (C col = b = l15); fp32 on VALU (exact); L0 wave only
  const float* xb = x + (size_t)(b0 + l15) * (T_STEPS * 2);
  float2 xpref = make_float2(0.f, 0.f);
  if (myL == 0) xpref = *reinterpret_cast<const float2*>(xb);

  // input-layer indices into hbuf for this wave's two matmuls
  const int inA = (myL == 2) ? 1 : 0;  // L0,L1 read h1; L2 reads h2
  const int inB = myL;                 // L1 reads h2; L2 reads h3 (unused for L0)

  __syncthreads();

  // ---- diagonal pipeline: iter s computes h1_s, h2_{s-1}, h3_{s-2} ----
  for (int s = 0; s < T_STEPS + 2; ++s) {
    const int cur = s & 1;
    const int nxt = cur ^ 1;

    const bool act = (myL == 0) ? (s < T_STEPS)
                   : (myL == 1) ? (s >= 1 && s <= T_STEPS)
                                : (s >= 2);

    if (act) {
      // read this wave's B-frags ONCE; reused by all 4 M-tiles
      bf16x8 bA[2][2], bB[2][2];  // [kstep][hi/lo]
#pragma unroll
      for (int ks = 0; ks < 2; ++ks)
#pragma unroll
        for (int h = 0; h < 2; ++h) {
          bA[ks][h] = *reinterpret_cast<const bf16x8*>(
              &hbuf[cur][inA][h][l15 * KST + 32 * ks + 8 * quad]);
          if (myL > 0)
            bB[ks][h] = *reinterpret_cast<const bf16x8*>(
                &hbuf[cur][inB][h][l15 * KST + 32 * ks + 8 * quad]);
        }

      f32x4 C[4];
      if (myL == 0) {
        float2 xc = xpref;
        int snext = (s + 1 < T_STEPS) ? s + 1 : T_STEPS - 1;
        xpref = *reinterpret_cast<const float2*>(xb + snext * 2);  // hide global latency
#pragma unroll
        for (int t = 0; t < 4; ++t)
#pragma unroll
          for (int r = 0; r < 4; ++r) C[t][r] = bs[t][r] + wx0[t][r] * xc.x + wx1[t][r] * xc.y;
      } else {
#pragma unroll
        for (int t = 0; t < 4; ++t)
#pragma unroll
          for (int r = 0; r < 4; ++r) C[t][r] = bs[t][r];
      }

      // 4 independent 6-deep chains (input A), + 4 more for input B when present
#pragma unroll
      for (int t = 0; t < 4; ++t)
#pragma unroll
        for (int ks = 0; ks < 2; ++ks) {
          C[t] = __builtin_amdgcn_mfma_f32_16x16x32_bf16(wAh[0][t][ks], bA[ks][0], C[t], 0, 0, 0);
          C[t] = __builtin_amdgcn_mfma_f32_16x16x32_bf16(wAh[0][t][ks], bA[ks][1], C[t], 0, 0, 0);
          C[t] = __builtin_amdgcn_mfma_f32_16x16x32_bf16(wAl[0][t][ks], bA[ks][0], C[t], 0, 0, 0);
        }
      if (myL > 0) {
        f32x4 Cb[4];
#pragma unroll
        for (int t = 0; t < 4; ++t)
#pragma unroll
          for (int r = 0; r < 4; ++r) Cb[t][r] = 0.0f;
#pragma unroll
        for (int t = 0; t < 4; ++t)
#pragma unroll
          for (int ks = 0; ks < 2; ++ks) {
            Cb[t] = __builtin_amdgcn_mfma_f32_16x16x32_bf16(wAh[1][t][ks], bB[ks][0], Cb[t], 0, 0, 0);
            Cb[t] = __builtin_amdgcn_mfma_f32_16x16x32_bf16(wAh[1][t][ks], bB[ks][1], Cb[t], 0, 0, 0);
            Cb[t] = __builtin_amdgcn_mfma_f32_16x16x32_bf16(wAl[1][t][ks], bB[ks][0], Cb[t], 0, 0, 0);
          }
#pragma unroll
        for (int t = 0; t < 4; ++t)
#pragma unroll
          for (int r = 0; r < 4; ++r) C[t][r] += Cb[t][r];
      }

      // tanh, split to hi/lo bf16, packed 8B writes (lane holds 4 consecutive i for one b)
#pragma unroll
      for (int t = 0; t < 4; ++t) {
        unsigned short hi[4], lo[4];
#pragma unroll
        for (int r = 0; r < 4; ++r) {
          float h = fast_tanh(C[t][r]);
          hi[r] = f2bf(h);
          lo[r] = f2bf(h - bf2f(hi[r]));
        }
        unsigned int h01 = (unsigned int)hi[0] | ((unsigned int)hi[1] << 16);
        unsigned int h23 = (unsigned int)hi[2] | ((unsigned int)hi[3] << 16);
        unsigned int l01 = (unsigned int)lo[0] | ((unsigned int)lo[1] << 16);
        unsigned int l23 = (unsigned int)lo[2] | ((unsigned int)lo[3] << 16);
        const int ioff = 16 * t + 4 * quad;
        *reinterpret_cast<uint2*>(&hbuf[nxt][myL][0][l15 * KST + ioff]) = make_uint2(h01, h23);
        *reinterpret_cast<uint2*>(&hbuf[nxt][myL][1][l15 * KST + ioff]) = make_uint2(l01, l23);
      }
    }
    __syncthreads();  // single barrier per iter: writes to nxt visible before next reads
  }

  // ---- fc epilogue: h3_255 landed in pp buffer 0 (written at s=257 -> nxt=0) ----
  if (tid < BT * 2) {
    int b = tid >> 1, o = tid & 1;
    const unsigned short* h3h = &hbuf[0][2][0][b * KST];
    const unsigned short* h3l = &hbuf[0][2][1][b * KST];
    float acc = fcb[o];
    for (int i = 0; i < HD; ++i)
      acc += fcw[o * HD + i] * (bf2f(h3h[i]) + bf2f(h3l[i]));
    out[(size_t)(b0 + b) * 2 + o] = acc;
  }
}

}  // namespace

extern "C" void kernel_launch(void* const* d_in, const int* in_sizes, int n_in,
                              void* d_out, int out_size, void* d_ws, size_t ws_size,
                              hipStream_t stream) {
  const float* x = (const float*)d_in[0];
  const float* Wih1 = (const float*)d_in[1];
  const float* Whh1 = (const float*)d_in[2];
  const float* bih1 = (const float*)d_in[3];
  const float* bhh1 = (const float*)d_in[4];
  const float* Wih2 = (const float*)d_in[5];
  const float* Whh2 = (const float*)d_in[6];
  const float* bih2 = (const float*)d_in[7];
  const float* bhh2 = (const float*)d_in[8];
  const float* Wih3 = (const float*)d_in[9];
  const float* Whh3 = (const float*)d_in[10];
  const float* bih3 = (const float*)d_in[11];
  const float* bhh3 = (const float*)d_in[12];
  const float* fcw = (const float*)d_in[13];
  const float* fcb = (const float*)d_in[14];

  rnn3_kernel<<<4096 / BT, NTHR, 0, stream>>>(x, Wih1, Whh1, bih1, bhh1,
                                              Wih2, Whh2, bih2, bhh2,
                                              Wih3, Whh3, bih3, bhh3,
                                              fcw, fcb, (float*)d_out);
}

// Round 4
// 278.715 us; speedup vs baseline: 1.4498x; 1.4498x over previous
//
#include <hip/hip_runtime.h>
#include <hip/hip_bf16.h>

namespace {

constexpr int T_STEPS = 256;
constexpr int HD = 50;   // hidden size
constexpr int HP = 64;   // padded hidden
constexpr int KST = 72;  // LDS row stride in bf16 elems
constexpr int BT = 16;   // batch tile per block
constexpr int NW = 12;   // waves: (layer, M-tile)
constexpr int NTHR = NW * 64;  // 768
constexpr int XST = 34;  // xls row stride in floats (odd dword stride -> conflict-free)

typedef __attribute__((ext_vector_type(8))) short bf16x8;
typedef __attribute__((ext_vector_type(4))) float f32x4;

__device__ __forceinline__ unsigned short f2bf(float x) {
  __hip_bfloat16 h = __float2bfloat16(x);
  return *reinterpret_cast<unsigned short*>(&h);
}
__device__ __forceinline__ float bf2f(unsigned short u) {
  __hip_bfloat16 h;
  *reinterpret_cast<unsigned short*>(&h) = u;
  return __bfloat162float(h);
}
__device__ __forceinline__ float fast_tanh(float x) {
  float e = __expf(2.0f * x);
  return 1.0f - 2.0f * __builtin_amdgcn_rcpf(e + 1.0f);
}

// Orientation: D[i][b] = sum_k W[i][k] * h[b][k]
//   A = weights, static in VGPRs; B = h from LDS; C/D row(i)=quad*4+reg, col(b)=lane&15
// Diagonal offsets 0/2/4: iter s computes h1_s, h2_{s-2}, h3_{s-4}.
// 3-slot LDS ring: writers use slot s%3; all reads in iter s touch slot (s+2)%3
// (data written at s-1) — cross-layer frags for iter s+1 also live in (s+2)%3,
// so they are REGISTER-PREFETCHED during iter s (latency off the serial chain).
__global__ __launch_bounds__(NTHR, 3) void rnn3_kernel(
    const float* __restrict__ x,
    const float* __restrict__ Wih1, const float* __restrict__ Whh1,
    const float* __restrict__ bih1, const float* __restrict__ bhh1,
    const float* __restrict__ Wih2, const float* __restrict__ Whh2,
    const float* __restrict__ bih2, const float* __restrict__ bhh2,
    const float* __restrict__ Wih3, const float* __restrict__ Whh3,
    const float* __restrict__ bih3, const float* __restrict__ bhh3,
    const float* __restrict__ fcw, const float* __restrict__ fcb,
    float* __restrict__ out) {
  __shared__ unsigned short hbuf[3][3][2][BT * KST];  // [ring][layer][hi/lo][b*KST+k]
  __shared__ float xls[T_STEPS][XST];                 // staged x, [t][2b(+pad)]
  __shared__ unsigned short scr[2][HP * KST];         // weight staging

  const int tid = threadIdx.x;
  const int w = tid >> 6;
  const int myL = w >> 2;         // layer 0..2
  const int wv = w & 3;           // M-tile
  const int lane = tid & 63;
  const int quad = lane >> 4;
  const int l15 = lane & 15;
  const int b0 = blockIdx.x * BT;

  // zero all 3 ring slots (initial h=0 and the k>=HD pad)
  {
    unsigned int* hz = reinterpret_cast<unsigned int*>(&hbuf[0][0][0][0]);
    const int n = 3 * 3 * 2 * BT * KST / 2;
    for (int i = tid; i < n; i += NTHR) hz[i] = 0u;
  }
  // stage x -> LDS (coalesced global reads; one-time LDS write conflicts are fine)
  for (int idx = tid; idx < BT * T_STEPS; idx += NTHR) {
    int b = idx >> 8, t = idx & 255;
    float2 v = *reinterpret_cast<const float2*>(x + (size_t)(b0 + b) * (T_STEPS * 2) + 2 * t);
    xls[t][2 * b] = v.x;
    xls[t][2 * b + 1] = v.y;
  }

  // ---- stage the five 50x50 matrices, split fp32 -> bf16 hi/lo ----
  const float* mats[5] = {Whh1, Wih2, Whh2, Wih3, Whh3};
  constexpr int matL[5] = {0, 1, 1, 2, 2};
  constexpr int matS[5] = {0, 0, 1, 0, 1};  // slot0 = cross (Wih), slot1 = self (Whh); L0: slot0 = Whh1 (self)
  bf16x8 wAh[2][2], wAl[2][2];  // [slot][kstep]
#pragma unroll
  for (int sl = 0; sl < 2; ++sl)
#pragma unroll
    for (int ks = 0; ks < 2; ++ks) { wAh[sl][ks] = bf16x8(0); wAl[sl][ks] = bf16x8(0); }

  const int arow = 16 * wv + l15;
#pragma unroll
  for (int m = 0; m < 5; ++m) {
    __syncthreads();
    const float* W = mats[m];
    for (int idx = tid; idx < HP * HP; idx += NTHR) {
      int i = idx >> 6, k = idx & 63;
      float v = (i < HD && k < HD) ? W[i * HD + k] : 0.0f;
      unsigned short hi = f2bf(v);
      scr[0][i * KST + k] = hi;
      scr[1][i * KST + k] = f2bf(v - bf2f(hi));
    }
    __syncthreads();
    if (myL == matL[m]) {
      const int sl = matS[m];
      const unsigned short* ph = &scr[0][arow * KST + 8 * quad];
      const unsigned short* pl = &scr[1][arow * KST + 8 * quad];
      wAh[sl][0] = *reinterpret_cast<const bf16x8*>(ph);
      wAh[sl][1] = *reinterpret_cast<const bf16x8*>(ph + 32);
      wAl[sl][0] = *reinterpret_cast<const bf16x8*>(pl);
      wAl[sl][1] = *reinterpret_cast<const bf16x8*>(pl + 32);
    }
  }

  // per-lane C-row constants
  const int ic = 16 * wv + 4 * quad;
  const float* bi = (myL == 0) ? bih1 : (myL == 1) ? bih2 : bih3;
  const float* bh = (myL == 0) ? bhh1 : (myL == 1) ? bhh2 : bhh3;
  float wx0[4], wx1[4], bs[4];
#pragma unroll
  for (int r = 0; r < 4; ++r) {
    int i = ic + r;
    bool v = i < HD;
    bs[r] = v ? (bi[i] + bh[i]) : 0.0f;
    wx0[r] = (v && myL == 0) ? Wih1[i * 2 + 0] : 0.0f;
    wx1[r] = (v && myL == 0) ? Wih1[i * 2 + 1] : 0.0f;
  }

  const int selfBuf = myL;               // L's own h
  const int crossBuf = (myL > 0) ? myL - 1 : 0;  // h from layer below (L1,L2)
  const int ldsOff = l15 * KST + 8 * quad;

  // cross-layer B-frags for the CURRENT iter, prefetched during the PREVIOUS iter
  bf16x8 pf[2][2];  // [kstep][hi/lo]
#pragma unroll
  for (int ks = 0; ks < 2; ++ks)
#pragma unroll
    for (int h = 0; h < 2; ++h) pf[ks][h] = bf16x8(0);

  __syncthreads();

  // ---- main loop: 260 iterations ----
  for (int s = 0; s < T_STEPS + 4; ++s) {
    const int wr = s % 3;        // write slot
    const int rd = (s + 2) % 3;  // slot holding data written at s-1

    const bool act = (myL == 0) ? (s < T_STEPS)
                   : (myL == 1) ? (s >= 2 && s < T_STEPS + 2)
                                : (s >= 4);

    // self-recurrent frags (written by sibling waves at s-1): read post-barrier
    bf16x8 bS[2][2];
#pragma unroll
    for (int ks = 0; ks < 2; ++ks)
#pragma unroll
      for (int h = 0; h < 2; ++h)
        bS[ks][h] = *reinterpret_cast<const bf16x8*>(
            &hbuf[rd][selfBuf][h][ldsOff + 32 * ks]);

    if (act) {
      f32x4 c1, c2;
      if (myL == 0) {
        // x from LDS (conflict-free row), exact fp32 input term
        float2 xc = *reinterpret_cast<const float2*>(&xls[s][2 * l15]);
#pragma unroll
        for (int r = 0; r < 4; ++r) {
          c1[r] = bs[r] + wx0[r] * xc.x + wx1[r] * xc.y;
          c2[r] = 0.0f;
        }
        // self chains only (Whh1), 2 independent 3-deep chains
        c1 = __builtin_amdgcn_mfma_f32_16x16x32_bf16(wAh[0][0], bS[0][0], c1, 0, 0, 0);
        c2 = __builtin_amdgcn_mfma_f32_16x16x32_bf16(wAh[0][1], bS[1][1], c2, 0, 0, 0);
        c1 = __builtin_amdgcn_mfma_f32_16x16x32_bf16(wAh[0][1], bS[1][0], c1, 0, 0, 0);
        c2 = __builtin_amdgcn_mfma_f32_16x16x32_bf16(wAl[0][0], bS[0][0], c2, 0, 0, 0);
        c1 = __builtin_amdgcn_mfma_f32_16x16x32_bf16(wAh[0][0], bS[0][1], c1, 0, 0, 0);
        c2 = __builtin_amdgcn_mfma_f32_16x16x32_bf16(wAl[0][1], bS[1][0], c2, 0, 0, 0);
#pragma unroll
        for (int r = 0; r < 4; ++r) c1[r] += c2[r];
      } else {
        // cross chains use PREFETCHED pf (no LDS latency on chain); self after
        f32x4 s1, s2;
#pragma unroll
        for (int r = 0; r < 4; ++r) { c1[r] = bs[r]; c2[r] = 0.0f; s1[r] = 0.0f; s2[r] = 0.0f; }
        c1 = __builtin_amdgcn_mfma_f32_16x16x32_bf16(wAh[0][0], pf[0][0], c1, 0, 0, 0);
        c2 = __builtin_amdgcn_mfma_f32_16x16x32_bf16(wAh[0][1], pf[1][1], c2, 0, 0, 0);
        c1 = __builtin_amdgcn_mfma_f32_16x16x32_bf16(wAh[0][1], pf[1][0], c1, 0, 0, 0);
        c2 = __builtin_amdgcn_mfma_f32_16x16x32_bf16(wAl[0][0], pf[0][0], c2, 0, 0, 0);
        c1 = __builtin_amdgcn_mfma_f32_16x16x32_bf16(wAh[0][0], pf[0][1], c1, 0, 0, 0);
        c2 = __builtin_amdgcn_mfma_f32_16x16x32_bf16(wAl[0][1], pf[1][0], c2, 0, 0, 0);
        s1 = __builtin_amdgcn_mfma_f32_16x16x32_bf16(wAh[1][0], bS[0][0], s1, 0, 0, 0);
        s2 = __builtin_amdgcn_mfma_f32_16x16x32_bf16(wAh[1][1], bS[1][1], s2, 0, 0, 0);
        s1 = __builtin_amdgcn_mfma_f32_16x16x32_bf16(wAh[1][1], bS[1][0], s1, 0, 0, 0);
        s2 = __builtin_amdgcn_mfma_f32_16x16x32_bf16(wAl[1][0], bS[0][0], s2, 0, 0, 0);
        s1 = __builtin_amdgcn_mfma_f32_16x16x32_bf16(wAh[1][0], bS[0][1], s1, 0, 0, 0);
        s2 = __builtin_amdgcn_mfma_f32_16x16x32_bf16(wAl[1][1], bS[1][0], s2, 0, 0, 0);
#pragma unroll
        for (int r = 0; r < 4; ++r) c1[r] = (c1[r] + c2[r]) + (s1[r] + s2[r]);
      }

      // tanh -> bf16 hi/lo -> packed 8B writes
      unsigned short hi[4], lo[4];
#pragma unroll
      for (int r = 0; r < 4; ++r) {
        float h = fast_tanh(c1[r]);
        hi[r] = f2bf(h);
        lo[r] = f2bf(h - bf2f(hi[r]));
      }
      unsigned int h01 = (unsigned int)hi[0] | ((unsigned int)hi[1] << 16);
      unsigned int h23 = (unsigned int)hi[2] | ((unsigned int)hi[3] << 16);
      unsigned int l01 = (unsigned int)lo[0] | ((unsigned int)lo[1] << 16);
      unsigned int l23 = (unsigned int)lo[2] | ((unsigned int)lo[3] << 16);
      *reinterpret_cast<uint2*>(&hbuf[wr][myL][0][l15 * KST + ic]) = make_uint2(h01, h23);
      *reinterpret_cast<uint2*>(&hbuf[wr][myL][1][l15 * KST + ic]) = make_uint2(l01, l23);
    }

    // prefetch cross frags for iter s+1 (data written at s-1, slot rd; writers
    // this iter use wr != rd -> race-free, issued pre-barrier, latency hidden)
    if (myL > 0) {
#pragma unroll
      for (int ks = 0; ks < 2; ++ks)
#pragma unroll
        for (int h = 0; h < 2; ++h)
          pf[ks][h] = *reinterpret_cast<const bf16x8*>(
              &hbuf[rd][crossBuf][h][ldsOff + 32 * ks]);
    }

    __syncthreads();
  }

  // ---- fc epilogue: h3_255 written at s=259 -> slot 259%3 = 1 ----
  if (tid < BT * 2) {
    int b = tid >> 1, o = tid & 1;
    const unsigned short* h3h = &hbuf[1][2][0][b * KST];
    const unsigned short* h3l = &hbuf[1][2][1][b * KST];
    float acc = fcb[o];
    for (int i = 0; i < HD; ++i)
      acc += fcw[o * HD + i] * (bf2f(h3h[i]) + bf2f(h3l[i]));
    out[(size_t)(b0 + b) * 2 + o] = acc;
  }
}

}  // namespace

extern "C" void kernel_launch(void* const* d_in, const int* in_sizes, int n_in,
                              void* d_out, int out_size, void* d_ws, size_t ws_size,
                              hipStream_t stream) {
  const float* x = (const float*)d_in[0];
  const float* Wih1 = (const float*)d_in[1];
  const float* Whh1 = (const float*)d_in[2];
  const float* bih1 = (const float*)d_in[3];
  const float* bhh1 = (const float*)d_in[4];
  const float* Wih2 = (const float*)d_in[5];
  const float* Whh2 = (const float*)d_in[6];
  const float* bih2 = (const float*)d_in[7];
  const float* bhh2 = (const float*)d_in[8];
  const float* Wih3 = (const float*)d_in[9];
  const float* Whh3 = (const float*)d_in[10];
  const float* bih3 = (const float*)d_in[11];
  const float* bhh3 = (const float*)d_in[12];
  const float* fcw = (const float*)d_in[13];
  const float* fcb = (const float*)d_in[14];

  rnn3_kernel<<<4096 / BT, NTHR, 0, stream>>>(x, Wih1, Whh1, bih1, bhh1,
                                              Wih2, Whh2, bih2, bhh2,
                                              Wih3, Whh3, bih3, bhh3,
                                              fcw, fcb, (float*)d_out);
}